// Round 8
// baseline (370.470 us; speedup 1.0000x reference)
//
#include <hip/hip_runtime.h>
#include <math.h>
#include <stdint.h>

#define NB 15
#define TROWS 512                 // rows per tile (2 per thread)
#define TBYTES (TROWS * 40)       // 20480 B per tile
#define NCOPY 8                   // spread accumulator copies (contention /8)
#define ACCSTRIDE 64              // floats per copy

// d_ws: NCOPY copies of {[0..14]=counts, [15..29]=sum_u, [30..44]=sum_err},
// then acc[NCOPY*ACCSTRIDE] = ticket counter (as int). All zeroed by one memset node.

__device__ __forceinline__ void gload_lds16(const void* g, float* ldsBase, uint32_t ldsByteOff)
{
    // async global->LDS, 16 B/lane; LDS dest = wave-uniform base + lane*16 (HW)
    __builtin_amdgcn_global_load_lds(
        (const __attribute__((address_space(1))) uint32_t*)g,
        (__attribute__((address_space(3))) uint32_t*)((char*)ldsBase + ldsByteOff),
        16, 0, 0);
}

__global__ __launch_bounds__(256) void bin_kernel(
    const float* __restrict__ logits,
    const int* __restrict__ labels,
    float* __restrict__ acc,
    float* __restrict__ out,
    int N, int numTiles, int nBlocks)
{
    __shared__ float lds[2 * TROWS * 10];   // 2 x 10240 B... (single 20480B tile buffer)
    __shared__ float s_acc[3 * NB];
    __shared__ int   s_last;

    const int t = threadIdx.x;
    if (t < 3 * NB) s_acc[t] = 0.0f;
    const int wid  = t >> 6;
    const int lane = t & 63;

    int   pk[NB];                          // count | (err<<16)  (<=5 tiles/thread)
    float su[NB];
#pragma unroll
    for (int b = 0; b < NB; ++b) { pk[b] = 0; su[b] = 0.0f; }

    const char* srcB = (const char*)logits;
    const long long totB = (long long)N * 40;

    for (int tile = blockIdx.x; tile < numTiles; tile += gridDim.x) {
        const long long tb = (long long)tile * TBYTES;

        const int r0 = tile * TROWS + t;
        const int r1 = r0 + 256;
        const int lab0 = (r0 < N) ? labels[r0] : 0;
        const int lab1 = (r1 < N) ? labels[r1] : 0;

        __syncthreads();                   // previous tile fully consumed
        // 20 chunks of 1024 B; 5 per wave, async DMA straight into LDS
#pragma unroll
        for (int k = 0; k < 5; ++k) {
            uint32_t loff = (uint32_t)(wid * 5 + k) << 10;     // wave-uniform
            long long gb = tb + loff + lane * 16;
            if (gb < totB)
                gload_lds16(srcB + gb, lds, __builtin_amdgcn_readfirstlane(loff));
        }
        __syncthreads();                   // vmcnt(0) drain + barrier -> LDS ready

        // ---- two rows per thread ----
        float a[10], b2[10];
        {
            const float2* p = (const float2*)(lds + t * 10);
#pragma unroll
            for (int j = 0; j < 5; ++j) { float2 w = p[j]; a[2*j] = w.x; a[2*j+1] = w.y; }
        }
        {
            const float2* p = (const float2*)(lds + (t + 256) * 10);
#pragma unroll
            for (int j = 0; j < 5; ++j) { float2 w = p[j]; b2[2*j] = w.x; b2[2*j+1] = w.y; }
        }
        float lvl0 = lds[t * 10 + lab0];           // label logit, dynamic LDS read
        float lvl1 = lds[(t + 256) * 10 + lab1];

        const float c = 1.44269504088896340736f;

        float mA = a[0];
#pragma unroll
        for (int j = 1; j < 10; ++j) mA = fmaxf(mA, a[j]);
        float mB = b2[0];
#pragma unroll
        for (int j = 1; j < 10; ++j) mB = fmaxf(mB, b2[j]);

        float mcA = mA * c, mcB = mB * c;
        float ZA = 0.f, SA = 0.f, ZB = 0.f, SB = 0.f;
#pragma unroll
        for (int j = 0; j < 10; ++j) {
            float eA = exp2f(fmaf(a[j],  c, -mcA));
            float eB = exp2f(fmaf(b2[j], c, -mcB));
            ZA += eA; SA = fmaf(eA, eA, SA);
            ZB += eB; SB = fmaf(eB, eB, SB);
        }
        float uA = -log2f(SA * __builtin_amdgcn_rcpf(ZA * ZA) + 1e-12f);
        float uB = -log2f(SB * __builtin_amdgcn_rcpf(ZB * ZB) + 1e-12f);

        bool vA = (r0 < N) && (uA >= 0.0f) && (uA < 1.0f);
        bool vB = (r1 < N) && (uB >= 0.0f) && (uB < 1.0f);
        int binA = -1, binB = -1;
        if (vA) { binA = (int)(uA * 15.0f); if (binA > 14) binA = 14; }
        if (vB) { binB = (int)(uB * 15.0f); if (binB > 14) binB = 14; }
        float uuA = vA ? uA : 0.0f;
        float uuB = vB ? uB : 0.0f;

        int eA10 = (lvl0 != mA) ? 1 : 0;           // wrong iff label's logit isn't the max
        int eB10 = (lvl1 != mB) ? 1 : 0;
        int incA = 1 + (eA10 << 16);
        int incB = 1 + (eB10 << 16);
#pragma unroll
        for (int b = 0; b < NB; ++b) {
            bool hA = (binA == b);
            bool hB = (binB == b);
            pk[b] += (hA ? incA : 0) + (hB ? incB : 0);
            su[b] += (hA ? uuA : 0.0f) + (hB ? uuB : 0.0f);
        }
    }

    // ---- once-per-block: wave butterfly -> shared atomics -> spread global atomics
#pragma unroll
    for (int b = 0; b < NB; ++b) {
        int   p = pk[b];
        float s = su[b];
#pragma unroll
        for (int off = 1; off < 64; off <<= 1) {
            p += __shfl_xor(p, off, 64);
            s += __shfl_xor(s, off, 64);
        }
        if (lane == 0) {
            atomicAdd(&s_acc[b],          (float)(p & 0xFFFF));
            atomicAdd(&s_acc[NB + b],     s);
            atomicAdd(&s_acc[2 * NB + b], (float)((unsigned)p >> 16));
        }
    }
    __syncthreads();
    if (t < 3 * NB) {
        float v = s_acc[t];
        if (v != 0.0f)
            atomicAdd(&acc[(blockIdx.x & (NCOPY - 1)) * ACCSTRIDE + t], v);
    }

    // ---- last-block finalize (folds the finalize kernel into this one) ----
    __threadfence();                       // data atomics visible before ticket
    __syncthreads();
    if (t == 0) {
        int old = atomicAdd((int*)(acc + NCOPY * ACCSTRIDE), 1);
        s_last = (old == nBlocks - 1) ? 1 : 0;
    }
    __syncthreads();
    if (s_last && t < 64) {
        int b = t;
        float gap = 0.0f;
        if (b < NB) {
            float cnt = 0.0f, sumu = 0.0f, serr = 0.0f;
#pragma unroll
            for (int cc = 0; cc < NCOPY; ++cc) {
                cnt  += atomicAdd(&acc[cc * ACCSTRIDE + b], 0.0f);       // coherent read
                sumu += atomicAdd(&acc[cc * ACCSTRIDE + NB + b], 0.0f);
                serr += atomicAdd(&acc[cc * ACCSTRIDE + 2 * NB + b], 0.0f);
            }
            if (cnt > 0.0f) {
                float u_b   = sumu / cnt;
                float err_b = serr / cnt;
                float inner = 2.0f * exp2f(-u_b) - 1.0f;
                if (inner < 0.0f) inner = 0.0f;
                float r_ref = 0.5f * (1.0f - sqrtf(inner));
                gap = fabsf(err_b - r_ref) * (cnt / (float)N);
            }
        }
#pragma unroll
        for (int off = 32; off >= 1; off >>= 1)
            gap += __shfl_xor(gap, off, 64);
        if (b == 0) out[0] = gap;
    }
}

extern "C" void kernel_launch(void* const* d_in, const int* in_sizes, int n_in,
                              void* d_out, int out_size, void* d_ws, size_t ws_size,
                              hipStream_t stream)
{
    const float* logits = (const float*)d_in[0];
    const int*   labels = (const int*)d_in[1];
    const int N = in_sizes[1];                  // labels count = number of rows

    float* acc = (float*)d_ws;                  // NCOPY*ACCSTRIDE floats + 1 int ticket
    hipMemsetAsync(acc, 0, (NCOPY * ACCSTRIDE + 1) * sizeof(float), stream);

    const int numTiles = (N + TROWS - 1) / TROWS;
    // 1792 = 7 blocks/CU (LDS-limited: 20480B + s_acc). Max 5 tiles/thread -> pk-safe.
    int blocks = numTiles < 1792 ? numTiles : 1792;
    bin_kernel<<<blocks, 256, 0, stream>>>(logits, labels, acc, (float*)d_out,
                                           N, numTiles, blocks);
}